// Round 9
// baseline (2610.594 us; speedup 1.0000x reference)
//
#include <hip/hip_runtime.h>
#include <hip/hip_bf16.h>

#define NBH     32          // B*H
#define SEQ     2048
#define DIM     64
#define QBLK    64
#define KBLK    128
#define NCHUNK  (SEQ / KBLK)     // 16
#define PSTR    136              // P row stride in ushorts (272B, 16B-aligned)

typedef __attribute__((ext_vector_type(4))) float f32x4;
typedef __attribute__((ext_vector_type(8))) short bf16x8;

__device__ __forceinline__ unsigned short bfbits(float f) {
    return __builtin_bit_cast(unsigned short, __float2bfloat16(f));
}

// ---------------------------------------------------------------------------
// V prep (unchanged from round 6)
// ---------------------------------------------------------------------------
__global__ __launch_bounds__(256)
void vprep_kernel(const float* __restrict__ v, unsigned short* __restrict__ wsv)
{
    const int blk = blockIdx.x;            // bh*32 + tau
    const int bh  = blk >> 5, tau = blk & 31;
    const float* vp = v + ((size_t)bh * SEQ + tau * 64) * DIM;
    unsigned short* op = wsv + (size_t)blk * 4096;

    for (int fl = threadIdx.x; fl < 512; fl += 256) {
        const int ks1 = fl >> 8, dt = (fl >> 6) & 3, lane = fl & 63;
        const int g = lane >> 4, c = lane & 15;
        const float* sp = vp + (ks1 * 32 + g * 8) * DIM + dt * 16 + c;
        bf16x8 frag;
#pragma unroll
        for (int j = 0; j < 8; ++j)
            frag[j] = (short)bfbits(sp[j * DIM]);
        *reinterpret_cast<bf16x8*>(op + fl * 8) = frag;
    }
}

// ---------------------------------------------------------------------------
// Main kernel (byte-identical to round 6, the 137.8us best)
// ---------------------------------------------------------------------------
__global__ __launch_bounds__(256, 2)
void softmaxv_kernel(const float* __restrict__ scores,
                     const unsigned short* __restrict__ vfrags,
                     float* __restrict__ out)
{
    __shared__ unsigned short p_lds[4][2][16 * PSTR];
    __shared__ float l_lds[4][16];

    const int tid  = threadIdx.x;
    const int w    = tid >> 6;
    const int lane = tid & 63;
    const int g    = lane >> 4;
    const int c    = lane & 15;
    const int h    = lane >> 5;
    const int c2   = lane & 31;

    const int bid = blockIdx.x;
    const int nb  = (bid & 7) * (NBH * 32 / 8) + (bid >> 3);
    const int bh  = nb >> 5;
    const int qb  = nb & 31;
    const int q0  = qb * QBLK;

    const float* sp = scores + ((size_t)bh * SEQ + q0 + w * 16 + h) * SEQ + c2 * 4;
    const unsigned short* vb = vfrags + (size_t)bh * 32 * 4096 + lane * 8;

    unsigned short* pb0 = &p_lds[w][0][0];
    unsigned short* pb1 = &p_lds[w][1][0];

    float lsum[8] = {0.f, 0.f, 0.f, 0.f, 0.f, 0.f, 0.f, 0.f};
    f32x4 acc[4];
#pragma unroll
    for (int dt = 0; dt < 4; ++dt) acc[dt] = (f32x4)0.0f;

#define SLOADS(dst, t)                                                         \
    {                                                                          \
        _Pragma("unroll")                                                      \
        for (int j = 0; j < 8; ++j)                                            \
            dst[j] = *reinterpret_cast<const f32x4*>(                          \
                sp + (size_t)(2 * j) * SEQ + (t) * KBLK);                      \
    }

#define VLOAD(vf, t)                                                           \
    {                                                                          \
        _Pragma("unroll")                                                      \
        for (int ks = 0; ks < 4; ++ks)                                         \
            _Pragma("unroll")                                                  \
            for (int dt = 0; dt < 4; ++dt)                                     \
                vf[ks][dt] = *reinterpret_cast<const bf16x8*>(                 \
                    vb + (size_t)(2 * (t) + (ks >> 1)) * 4096 +                \
                    ((ks & 1) * 4 + dt) * 512);                                \
    }

#define PROC(sreg, pbuf)                                                       \
    {                                                                          \
        _Pragma("unroll")                                                      \
        for (int j = 0; j < 8; ++j) {                                          \
            f32x4 s4 = sreg[j];                                                \
            float p0 = __expf(s4[0]);                                          \
            float p1 = __expf(s4[1]);                                          \
            float p2 = __expf(s4[2]);                                          \
            float p3 = __expf(s4[3]);                                          \
            lsum[j] += (p0 + p1) + (p2 + p3);                                  \
            unsigned lo = (unsigned)bfbits(p0) | ((unsigned)bfbits(p1) << 16); \
            unsigned hi = (unsigned)bfbits(p2) | ((unsigned)bfbits(p3) << 16); \
            *reinterpret_cast<uint2*>(&pbuf[(2 * j + h) * PSTR + c2 * 4]) =    \
                make_uint2(lo, hi);                                            \
        }                                                                      \
        _Pragma("unroll")                                                      \
        for (int ks = 0; ks < 4; ++ks) {                                       \
            const bf16x8 a = *reinterpret_cast<const bf16x8*>(                 \
                &pbuf[c * PSTR + ks * 32 + g * 8]);                            \
            _Pragma("unroll")                                                  \
            for (int dt = 0; dt < 4; ++dt)                                     \
                acc[dt] = __builtin_amdgcn_mfma_f32_16x16x32_bf16(             \
                    a, vf[ks][dt], acc[dt], 0, 0, 0);                          \
        }                                                                      \
    }

    f32x4 sA[8], sB[8];
    bf16x8 vf[4][4];
    SLOADS(sA, 0)
    for (int t = 0; t < NCHUNK; t += 2) {
        VLOAD(vf, t)
        SLOADS(sB, t + 1)
        PROC(sA, pb0)
        VLOAD(vf, t + 1)
        if (t + 2 < NCHUNK) SLOADS(sA, t + 2)
        PROC(sB, pb1)
    }
#undef SLOADS
#undef VLOAD
#undef PROC

#pragma unroll
    for (int j = 0; j < 8; ++j) {
        float l = lsum[j];
        l += __shfl_xor(l, 1);
        l += __shfl_xor(l, 2);
        l += __shfl_xor(l, 4);
        l += __shfl_xor(l, 8);
        l += __shfl_xor(l, 16);
        if (c2 == j) l_lds[w][2 * j + h] = l;
    }

    float* op = out + ((size_t)bh * SEQ + q0 + w * 16) * DIM;
    float rl[4];
#pragma unroll
    for (int r = 0; r < 4; ++r)
        rl[r] = 1.0f / l_lds[w][g * 4 + r];
#pragma unroll
    for (int dt = 0; dt < 4; ++dt)
#pragma unroll
        for (int r = 0; r < 4; ++r)
            op[(g * 4 + r) * DIM + dt * 16 + c] = acc[dt][r] * rl[r];
}

// ---------------------------------------------------------------------------
// PROBE C: COLD pattern-read over ~2 GiB of ws, exact main-kernel S geometry
// (XCD swizzle, 64 row-streams/block, 8KB stride, 512B visits), 2 blocks/CU.
// 2 reps (rep 2 ~87% cold). 4.03 GB logical.
// ---------------------------------------------------------------------------
#define PBLK 4032            // 4032 * 512KB = 2.016 GiB, 4032 % 8 == 0

__global__ __launch_bounds__(256, 2)
void probe_c_kernel(const float* __restrict__ base, float* __restrict__ sink)
{
    const int tid  = threadIdx.x;
    const int w    = tid >> 6;
    const int lane = tid & 63;
    const int h    = lane >> 5;
    const int c2   = lane & 31;

    const int bid = blockIdx.x;
    const int nb  = (bid & 7) * (PBLK / 8) + (bid >> 3);   // XCD swizzle, bijective
    const float* sp = base + (size_t)nb * 131072 + (w * 16 + h) * 2048 + c2 * 4;

    f32x4 acc = (f32x4)0.0f;
    for (int rep = 0; rep < 2; ++rep) {
        for (int t = 0; t < 16; ++t) {
#pragma unroll
            for (int j = 0; j < 8; ++j)
                acc += *reinterpret_cast<const f32x4*>(
                    sp + (size_t)(2 * j) * 2048 + t * 128);
        }
    }
    sink[(size_t)bid * 256 + tid] = acc[0] + acc[1] + acc[2] + acc[3];
}

// ---------------------------------------------------------------------------
// PROBE E: identical pattern, but 4 blocks/CU residency (occupancy lever).
// ---------------------------------------------------------------------------
__global__ __launch_bounds__(256, 4)
void probe_e_kernel(const float* __restrict__ base, float* __restrict__ sink)
{
    const int tid  = threadIdx.x;
    const int w    = tid >> 6;
    const int lane = tid & 63;
    const int h    = lane >> 5;
    const int c2   = lane & 31;

    const int bid = blockIdx.x;
    const int nb  = (bid & 7) * (PBLK / 8) + (bid >> 3);
    const float* sp = base + (size_t)nb * 131072 + (w * 16 + h) * 2048 + c2 * 4;

    f32x4 acc = (f32x4)0.0f;
    for (int rep = 0; rep < 2; ++rep) {
        for (int t = 0; t < 16; ++t) {
#pragma unroll
            for (int j = 0; j < 8; ++j)
                acc += *reinterpret_cast<const f32x4*>(
                    sp + (size_t)(2 * j) * 2048 + t * 128);
        }
    }
    sink[(size_t)bid * 256 + tid] = acc[0] + acc[1] + acc[2] + acc[3];
}

extern "C" void kernel_launch(void* const* d_in, const int* in_sizes, int n_in,
                              void* d_out, int out_size, void* d_ws, size_t ws_size,
                              hipStream_t stream)
{
    const float* scores = (const float*)d_in[0];
    const float* v      = (const float*)d_in[1];
    float* out          = (float*)d_out;
    unsigned short* wsv = (unsigned short*)d_ws;                        // 8 MB

    // probe read span: ws[0 .. 2.016 GiB); sinks near the 2 GiB tail
    const float* pbase = (const float*)d_ws;
    float* sinkC = (float*)((char*)d_ws + (2113929216ull));             // 2 GiB - 32 MiB
    float* sinkE = (float*)((char*)d_ws + (2113929216ull + (16u << 20)));

    vprep_kernel<<<dim3(NBH * 32), dim3(256), 0, stream>>>(v, wsv);
    softmaxv_kernel<<<dim3(NBH * (SEQ / QBLK)), dim3(256), 0, stream>>>(scores, wsv, out);
    // --- sacrificial cold-read probes (do not touch d_out) ---
    probe_c_kernel<<<dim3(PBLK), dim3(256), 0, stream>>>(pbase, sinkC);
    probe_e_kernel<<<dim3(PBLK), dim3(256), 0, stream>>>(pbase, sinkE);
}

// Round 11
// 202.306 us; speedup vs baseline: 12.9042x; 12.9042x over previous
//
#include <hip/hip_runtime.h>
#include <hip/hip_bf16.h>

#define NBH   32          // B*H
#define SEQ   2048
#define DIM   64
#define QBLK  64
#define PCOLS 136         // padded panel row stride in ushorts (272B)

typedef __attribute__((ext_vector_type(4))) float f32x4;
typedef __attribute__((ext_vector_type(8))) short bf16x8;
typedef __attribute__((ext_vector_type(4))) unsigned int u32x4;

__device__ __forceinline__ unsigned short bfbits(float f) {
    return __builtin_bit_cast(unsigned short, __float2bfloat16(f));
}
__device__ __forceinline__ unsigned pk(float a, float b) {
    return (unsigned)bfbits(a) | ((unsigned)bfbits(b) << 16);
}

// ---------------------------------------------------------------------------
// V prep (unchanged): ws[bh][tau][ks][dt][lane][j] = bf16 of
//   V[bh][tau*64 + ks*32 + (lane>>4)*8 + j][dt*16 + (lane&15)]
// ---------------------------------------------------------------------------
__global__ __launch_bounds__(256)
void vprep_kernel(const float* __restrict__ v, unsigned short* __restrict__ wsv)
{
    const int blk = blockIdx.x;            // bh*32 + tau
    const int bh  = blk >> 5, tau = blk & 31;
    const float* vp = v + ((size_t)bh * SEQ + tau * 64) * DIM;
    unsigned short* op = wsv + (size_t)blk * 4096;

    for (int fl = threadIdx.x; fl < 512; fl += 256) {
        const int ks = fl >> 8, dt = (fl >> 6) & 3, lane = fl & 63;
        const int g = lane >> 4, c = lane & 15;
        const float* sp = vp + (ks * 32 + g * 8) * DIM + dt * 16 + c;
        bf16x8 frag;
#pragma unroll
        for (int j = 0; j < 8; ++j)
            frag[j] = (short)bfbits(sp[j * DIM]);
        *reinterpret_cast<bf16x8*>(op + fl * 8) = frag;
    }
}

// ---------------------------------------------------------------------------
// Main kernel: block reads its 512KB S-slab FULLY SEQUENTIALLY (probe-B
// pattern): thread t owns cols [t*8, t*8+8) of every row; rows in order.
// Transpose via LDS k-panels (16 panels of [16 rows][128 cols], padded).
// Wave w MFMAs output-column slice dt=w for all 4 row-tiles. Ones-column
// MFMA gives the denominator in the exact epilogue lane layout. Barriers
// are LDS-only (no vmcnt drain) so the S prefetch rides through them.
// FIX vs round 10: consume stage slot BEFORE issuing its replacement.
// ---------------------------------------------------------------------------
__global__ __launch_bounds__(256, 2)
void softmaxv_kernel(const float* __restrict__ scores,
                     const unsigned short* __restrict__ vfrags,
                     float* __restrict__ out)
{
    __shared__ unsigned short panels[16][16 * PCOLS];   // 69632 B

    const int tid  = threadIdx.x;
    const int w    = tid >> 6;        // wave = output dt slice
    const int lane = tid & 63;
    const int g    = lane >> 4;       // 0..3
    const int c    = lane & 15;       // 0..15

    const int bid = blockIdx.x;
    const int nb  = (bid & 7) * 128 + (bid >> 3);   // XCD swizzle (1024%8==0)
    const int bh  = nb >> 5;
    const int qb  = nb & 31;
    const int q0  = qb * QBLK;

    const float* sbase = scores + ((size_t)bh * SEQ + q0) * SEQ + tid * 8;
    const unsigned short* vb = vfrags + (size_t)bh * 32 * 4096 + lane * 8;

    f32x4 acc[4], accl[4];
#pragma unroll
    for (int rt = 0; rt < 4; ++rt) { acc[rt] = (f32x4)0.0f; accl[rt] = (f32x4)0.0f; }
    bf16x8 ones;
#pragma unroll
    for (int j = 0; j < 8; ++j) ones[j] = (short)0x3F80;   // bf16 1.0

    f32x4 s0[4], s1[4];               // 4-row-deep stage, slot = row & 3

#define ISSUE(row)                                                             \
    {                                                                          \
        s0[(row) & 3] = *reinterpret_cast<const f32x4*>(                       \
            sbase + (size_t)(row) * SEQ);                                      \
        s1[(row) & 3] = *reinterpret_cast<const f32x4*>(                       \
            sbase + (size_t)(row) * SEQ + 4);                                  \
    }

#define VF(dst, kk)                                                            \
    {                                                                          \
        _Pragma("unroll")                                                      \
        for (int ks = 0; ks < 4; ++ks)                                         \
            dst[ks] = *reinterpret_cast<const bf16x8*>(                        \
                vb + (size_t)(2 * (kk) + (ks >> 1)) * 4096 +                   \
                ((ks & 1) * 4 + w) * 512);                                     \
    }

#define KSTEP(VBUF, kk)                                                        \
    {                                                                          \
        _Pragma("unroll")                                                      \
        for (int ks = 0; ks < 4; ++ks) {                                       \
            const bf16x8 afrag = *reinterpret_cast<const bf16x8*>(             \
                &panels[kk][c * PCOLS + ks * 32 + g * 8]);                     \
            acc[rt] = __builtin_amdgcn_mfma_f32_16x16x32_bf16(                 \
                afrag, VBUF[ks], acc[rt], 0, 0, 0);                            \
            accl[rt] = __builtin_amdgcn_mfma_f32_16x16x32_bf16(                \
                afrag, ones, accl[rt], 0, 0, 0);                               \
        }                                                                      \
    }

#define LDS_BAR asm volatile("s_waitcnt lgkmcnt(0)\n\ts_barrier" ::: "memory");

    ISSUE(0) ISSUE(1) ISSUE(2) ISSUE(3)

    bf16x8 vfA[4], vfB[4];

#pragma unroll
    for (int rt = 0; rt < 4; ++rt) {
        // ---- read+exp+pack 16 rows, sequential slab order, write panels ----
#pragma unroll
        for (int r = 0; r < 16; ++r) {
            const f32x4 a = s0[r & 3], b = s1[r & 3];   // consume FIRST
            if (rt * 16 + r + 4 < 64) ISSUE(rt * 16 + r + 4)   // then refill slot
            const float e0 = __expf(a[0]), e1 = __expf(a[1]);
            const float e2 = __expf(a[2]), e3 = __expf(a[3]);
            const float e4 = __expf(b[0]), e5 = __expf(b[1]);
            const float e6 = __expf(b[2]), e7 = __expf(b[3]);
            u32x4 p;
            p[0] = pk(e0, e1); p[1] = pk(e2, e3);
            p[2] = pk(e4, e5); p[3] = pk(e6, e7);
            *reinterpret_cast<u32x4*>(
                &panels[tid >> 4][r * PCOLS + (tid & 15) * 8]) = p;
        }

        LDS_BAR   // panel writes visible; S prefetch stays in flight

        // ---- MFMA all 16 k-panels (wave w does its dt slice + denominator) --
        VF(vfA, 0)
#pragma unroll
        for (int kk2 = 0; kk2 < 8; ++kk2) {
            VF(vfB, 2 * kk2 + 1)
            KSTEP(vfA, 2 * kk2)
            if (kk2 < 7) VF(vfA, 2 * kk2 + 2)
            KSTEP(vfB, 2 * kk2 + 1)
        }

        LDS_BAR   // panel reads done before next row-tile overwrites
    }
#undef ISSUE
#undef VF
#undef KSTEP
#undef LDS_BAR

    // ---- epilogue: accl is the denominator in matching lane layout ----
    float* op = out + ((size_t)bh * SEQ + q0) * DIM + w * 16 + c;
#pragma unroll
    for (int rt = 0; rt < 4; ++rt) {
#pragma unroll
        for (int r = 0; r < 4; ++r)
            op[(size_t)(rt * 16 + g * 4 + r) * DIM] = acc[rt][r] * (1.0f / accl[rt][r]);
    }
}

extern "C" void kernel_launch(void* const* d_in, const int* in_sizes, int n_in,
                              void* d_out, int out_size, void* d_ws, size_t ws_size,
                              hipStream_t stream)
{
    const float* scores = (const float*)d_in[0];
    const float* v      = (const float*)d_in[1];
    float* out          = (float*)d_out;
    unsigned short* wsv = (unsigned short*)d_ws;   // 8 MB of ws used

    vprep_kernel<<<dim3(NBH * 32), dim3(256), 0, stream>>>(v, wsv);
    softmaxv_kernel<<<dim3(NBH * (SEQ / QBLK)), dim3(256), 0, stream>>>(scores, wsv, out);
}

// Round 12
// 149.131 us; speedup vs baseline: 17.5053x; 1.3566x over previous
//
#include <hip/hip_runtime.h>
#include <hip/hip_bf16.h>

#define NBH   32          // B*H
#define SEQ   2048
#define DIM   64
#define PCOLS 136                 // ushorts per panel row (272B)
#define PANEL (16 * PCOLS)        // ushorts per panel (16 rows)
#define BUFSZ (16 * PANEL)        // ushorts per buffer (16 panels)

typedef __attribute__((ext_vector_type(4))) float f32x4;
typedef __attribute__((ext_vector_type(8))) short bf16x8;
typedef __attribute__((ext_vector_type(4))) unsigned int u32x4;

__device__ __forceinline__ unsigned short bfbits(float f) {
    return __builtin_bit_cast(unsigned short, __float2bfloat16(f));
}
__device__ __forceinline__ unsigned pk(float a, float b) {
    return (unsigned)bfbits(a) | ((unsigned)bfbits(b) << 16);
}

// ---------------------------------------------------------------------------
// V prep (unchanged): ws[bh][tau][ks][dt][lane][j] = bf16 of
//   V[bh][tau*64 + ks*32 + (lane>>4)*8 + j][dt*16 + (lane&15)]
// ---------------------------------------------------------------------------
__global__ __launch_bounds__(256)
void vprep_kernel(const float* __restrict__ v, unsigned short* __restrict__ wsv)
{
    const int blk = blockIdx.x;            // bh*32 + tau
    const int bh  = blk >> 5, tau = blk & 31;
    const float* vp = v + ((size_t)bh * SEQ + tau * 64) * DIM;
    unsigned short* op = wsv + (size_t)blk * 4096;

    for (int fl = threadIdx.x; fl < 512; fl += 256) {
        const int ks = fl >> 8, dt = (fl >> 6) & 3, lane = fl & 63;
        const int g = lane >> 4, c = lane & 15;
        const float* sp = vp + (ks * 32 + g * 8) * DIM + dt * 16 + c;
        bf16x8 frag;
#pragma unroll
        for (int j = 0; j < 8; ++j)
            frag[j] = (short)bfbits(sp[j * DIM]);
        *reinterpret_cast<bf16x8*>(op + fl * 8) = frag;
    }
}

// ---------------------------------------------------------------------------
// Main kernel: PERSISTENT producer/consumer blocks. 256 blocks x 512 threads,
// 1 per CU. Block (bh = bid%32, s = bid/32) owns S rows [s*256, s*256+256)
// of head bh: a contiguous 2MB slab, streamed fully sequentially by waves
// 0-3 (producers: load -> exp -> pack bf16 -> LDS k-panels, double-buffered).
// Waves 4-7 (consumers) MFMA the panels against pre-packed V fragments,
// wave w owning output cols [(w-4)*16, (w-4)*16+16). Ones-column MFMA forms
// the softmax denominator. Barriers are lgkm-only: producer vmcnt pipeline
// (depth-4 row ring) rides through all 17 phases without draining.
// ---------------------------------------------------------------------------
__global__ __launch_bounds__(512, 2)
void softmaxv_kernel(const float* __restrict__ scores,
                     const unsigned short* __restrict__ vfrags,
                     float* __restrict__ out)
{
    __shared__ unsigned short panels[2 * BUFSZ];   // 139,264 B (double buffer)

    const int tid = threadIdx.x;
    const int bid = blockIdx.x;
    const int bh  = bid & 31;      // same-bh blocks share an XCD (bid%8 = bh%8)
    const int s   = bid >> 5;      // 0..7 -> q-range [s*256, s*256+256)

#define LDS_BAR asm volatile("s_waitcnt lgkmcnt(0)\n\ts_barrier" ::: "memory");

    if (tid < 256) {
        // =================== PRODUCER (waves 0-3) ===========================
        // thread owns k-cols [tid*8, tid*8+8) of every row; rows in order.
        const float* sbase = scores + ((size_t)bh * SEQ + s * 256) * SEQ + tid * 8;
        unsigned short* const mybase = panels + (tid >> 4) * PANEL + (tid & 15) * 8;

        f32x4 s0[4], s1[4];        // depth-4 row ring, statically indexed
#define ISSUE(R, slot)                                                         \
        {                                                                      \
            s0[slot] = *reinterpret_cast<const f32x4*>(                        \
                sbase + (size_t)(R) * SEQ);                                    \
            s1[slot] = *reinterpret_cast<const f32x4*>(                        \
                sbase + (size_t)(R) * SEQ + 4);                                \
        }
        ISSUE(0, 0) ISSUE(1, 1) ISSUE(2, 2) ISSUE(3, 3)

        for (int p = 0; p < 17; ++p) {
            if (p < 16) {
                unsigned short* const pb = mybase + (p & 1) * BUFSZ;
#pragma unroll
                for (int r = 0; r < 16; ++r) {
                    const f32x4 a = s0[r & 3], b = s1[r & 3];   // consume first
                    const int R = p * 16 + r;
                    if (R + 4 < 256) ISSUE(R + 4, r & 3)        // then refill
                    const float e0 = __expf(a[0]), e1 = __expf(a[1]);
                    const float e2 = __expf(a[2]), e3 = __expf(a[3]);
                    const float e4 = __expf(b[0]), e5 = __expf(b[1]);
                    const float e6 = __expf(b[2]), e7 = __expf(b[3]);
                    u32x4 pw;
                    pw[0] = pk(e0, e1); pw[1] = pk(e2, e3);
                    pw[2] = pk(e4, e5); pw[3] = pk(e6, e7);
                    *reinterpret_cast<u32x4*>(pb + r * PCOLS) = pw;
                }
            }
            LDS_BAR
        }
#undef ISSUE
    } else {
        // =================== CONSUMER (waves 4-7) ===========================
        const int dt   = (tid >> 6) - 4;   // output col slice
        const int lane = tid & 63;
        const int g    = lane >> 4;        // 0..3
        const int c    = lane & 15;        // 0..15

        const unsigned short* vb = vfrags + (size_t)bh * 32 * 4096 + lane * 8;
        bf16x8 ones;
#pragma unroll
        for (int j = 0; j < 8; ++j) ones[j] = (short)0x3F80;   // bf16 1.0

        float* const ob = out + ((size_t)bh * SEQ + s * 256) * DIM + dt * 16 + c;

#define VF(dst, kk)                                                            \
        {                                                                      \
            _Pragma("unroll")                                                  \
            for (int ks = 0; ks < 4; ++ks)                                     \
                dst[ks] = *reinterpret_cast<const bf16x8*>(                    \
                    vb + (size_t)(2 * (kk) + (ks >> 1)) * 4096 +               \
                    ((ks & 1) * 4 + dt) * 512);                                \
        }

#define KSTEP(VBUF, kk)                                                        \
        {                                                                      \
            _Pragma("unroll")                                                  \
            for (int ks = 0; ks < 4; ++ks) {                                   \
                const bf16x8 afrag = *reinterpret_cast<const bf16x8*>(         \
                    cb + (kk) * PANEL + ks * 32);                              \
                acc = __builtin_amdgcn_mfma_f32_16x16x32_bf16(                 \
                    afrag, VBUF[ks], acc, 0, 0, 0);                            \
                accl = __builtin_amdgcn_mfma_f32_16x16x32_bf16(                \
                    afrag, ones, accl, 0, 0, 0);                               \
            }                                                                  \
        }

        for (int p = 0; p < 17; ++p) {
            if (p >= 1) {
                const int T = p - 1;
                const unsigned short* const cb =
                    panels + (T & 1) * BUFSZ + c * PCOLS + g * 8;
                f32x4 acc  = (f32x4)0.0f;
                f32x4 accl = (f32x4)0.0f;
                bf16x8 vfA[4], vfB[4];
                VF(vfA, 0)
#pragma unroll
                for (int kk2 = 0; kk2 < 8; ++kk2) {
                    VF(vfB, 2 * kk2 + 1)
                    KSTEP(vfA, 2 * kk2)
                    if (kk2 < 7) VF(vfA, 2 * kk2 + 2)
                    KSTEP(vfB, 2 * kk2 + 1)
                }
                float* const op = ob + (size_t)(T * 16) * DIM;
#pragma unroll
                for (int r = 0; r < 4; ++r)
                    op[(size_t)(g * 4 + r) * DIM] = acc[r] * (1.0f / accl[r]);
            }
            LDS_BAR
        }
#undef VF
#undef KSTEP
    }
#undef LDS_BAR
}

extern "C" void kernel_launch(void* const* d_in, const int* in_sizes, int n_in,
                              void* d_out, int out_size, void* d_ws, size_t ws_size,
                              hipStream_t stream)
{
    const float* scores = (const float*)d_in[0];
    const float* v      = (const float*)d_in[1];
    float* out          = (float*)d_out;
    unsigned short* wsv = (unsigned short*)d_ws;   // 8 MB of ws used

    vprep_kernel<<<dim3(NBH * 32), dim3(256), 0, stream>>>(v, wsv);
    softmaxv_kernel<<<dim3(256), dim3(512), 0, stream>>>(scores, wsv, out);
}